// Round 1
// baseline (460.204 us; speedup 1.0000x reference)
//
#include <hip/hip_runtime.h>
#include <stdint.h>

typedef __bf16 bf16_t;
typedef __bf16 bf16x8 __attribute__((ext_vector_type(8)));
typedef float f32x4 __attribute__((ext_vector_type(4)));
typedef unsigned short us16x8 __attribute__((ext_vector_type(8)));

#define MFMA16(a, b, c) __builtin_amdgcn_mfma_f32_16x16x32_bf16(a, b, c, 0, 0, 0)

__device__ __forceinline__ void stage16(const bf16_t* g, bf16_t* l) {
#if __has_builtin(__builtin_amdgcn_global_load_lds)
  __builtin_amdgcn_global_load_lds((__attribute__((address_space(1))) void*)g,
                                   (__attribute__((address_space(3))) void*)l, 16, 0, 0);
#else
  *(bf16x8*)l = *(const bf16x8*)g;
#endif
}

// ---------------- f32 -> bf16 conversion ----------------
__global__ __launch_bounds__(256) void cvt_f32_to_bf16(const float* __restrict__ in,
                                                       bf16_t* __restrict__ out, int n8) {
  int i = blockIdx.x * 256 + threadIdx.x;
  if (i >= n8) return;
  const f32x4* p = (const f32x4*)(in + (size_t)i * 8);
  f32x4 a = p[0], b = p[1];
  bf16x8 o;
  o[0] = (bf16_t)a[0]; o[1] = (bf16_t)a[1]; o[2] = (bf16_t)a[2]; o[3] = (bf16_t)a[3];
  o[4] = (bf16_t)b[0]; o[5] = (bf16_t)b[1]; o[6] = (bf16_t)b[2]; o[7] = (bf16_t)b[3];
  *(bf16x8*)(out + (size_t)i * 8) = o;
}

// ---------------- NT GEMM: C[M,N] = A[M,K] * B[N,K]^T + bias ----------------
// 128x128 tile, BK=64, 4 waves (2x2), each wave 64x64 (4x4 16x16 frags).
// LDS swizzle: within each 64-elem row (8 blocks of 8 bf16), block index XOR (row&7),
// applied on the GLOBAL source address (global_load_lds dest stays linear) and on reads.
template <int OUT_BF16>
__global__ __launch_bounds__(256) void gemm_nt(const bf16_t* __restrict__ A,
                                               const bf16_t* __restrict__ B,
                                               const float* __restrict__ bias,
                                               void* __restrict__ Cout,
                                               int M, int N, int K) {
  __shared__ bf16_t As[128 * 64];
  __shared__ bf16_t Bs[128 * 64];
  int tid = threadIdx.x;
  int l = tid & 63, w = tid >> 6;
  int wr = w >> 1, wc = w & 1;
  int nbn = N >> 7;
  int bm = blockIdx.x / nbn, bn = blockIdx.x % nbn;
  int l15 = l & 15, l4 = l >> 4, l7 = l & 7;

  f32x4 acc[4][4] = {};

  for (int ks = 0; ks < K; ks += 64) {
#pragma unroll
    for (int i = 0; i < 4; ++i) {
      int e = i * 256 + tid;
      int row = e >> 3, blk = e & 7;
      int col = ks + ((blk ^ (row & 7)) << 3);
      stage16(A + (size_t)(bm * 128 + row) * K + col, As + e * 8);
      stage16(B + (size_t)(bn * 128 + row) * K + col, Bs + e * 8);
    }
    __syncthreads();
#pragma unroll
    for (int kk = 0; kk < 2; ++kk) {
      bf16x8 af[4], bfr[4];
      int blk = (kk * 4 + l4) ^ l7;
#pragma unroll
      for (int m = 0; m < 4; ++m) {
        af[m] = *(const bf16x8*)(As + (wr * 64 + m * 16 + l15) * 64 + blk * 8);
        bfr[m] = *(const bf16x8*)(Bs + (wc * 64 + m * 16 + l15) * 64 + blk * 8);
      }
#pragma unroll
      for (int m = 0; m < 4; ++m)
#pragma unroll
        for (int n = 0; n < 4; ++n)
          acc[m][n] = MFMA16(af[m], bfr[n], acc[m][n]);
    }
    __syncthreads();
  }

  int rbase = bm * 128 + wr * 64 + (l4 << 2);
  int cbase = bn * 128 + wc * 64 + l15;
#pragma unroll
  for (int n = 0; n < 4; ++n) {
    float bv = bias[cbase + n * 16];
#pragma unroll
    for (int m = 0; m < 4; ++m)
#pragma unroll
      for (int r = 0; r < 4; ++r) {
        float v = acc[m][n][r] + bv;
        size_t off = (size_t)(rbase + m * 16 + r) * N + (cbase + n * 16);
        if (OUT_BF16) ((bf16_t*)Cout)[off] = (bf16_t)v;
        else ((float*)Cout)[off] = v;
      }
  }
}

// ---------------- causal flash attention ----------------
// qkv: [4096, 6144] bf16 (q at col h*128, k at 2048+h*128, v at 4096+h*128)
// att: [4096, 2048] bf16. Block = (b, h, q-tile of 128). 4 waves x 32 q-rows.
__global__ __launch_bounds__(256) void attn_fwd(const bf16_t* __restrict__ qkv,
                                                bf16_t* __restrict__ att) {
  __shared__ bf16_t Kt[64 * 128];     // [krow][d], block-swizzled rows of 128
  __shared__ bf16_t Vt[128 * 64];     // transposed [d][k], block-swizzled rows of 64
  __shared__ bf16_t Pl[4][32 * 72];   // per-wave P scratch, padded rows (16B-aligned)

  int bid = blockIdx.x;
  int qt = bid & 15, h = (bid >> 4) & 15, b = bid >> 8;
  int tid = threadIdx.x;
  int l = tid & 63, w = tid >> 6;
  int l15 = l & 15, l4 = l >> 4, l7 = l & 7;
  int q0 = qt * 128, wq0 = q0 + w * 32;
  const size_t LD = 6144;

  // Q fragments in registers: [m2][kk] (A-operand layout)
  bf16x8 qf[2][4];
#pragma unroll
  for (int m2 = 0; m2 < 2; ++m2)
#pragma unroll
    for (int kk = 0; kk < 4; ++kk)
      qf[m2][kk] = *(const bf16x8*)(qkv + (size_t)(b * 2048 + wq0 + m2 * 16 + l15) * LD +
                                    h * 128 + kk * 32 + l4 * 8);

  f32x4 acc[2][8] = {};
  float mrow[2][4], lrow[2][4];
#pragma unroll
  for (int m2 = 0; m2 < 2; ++m2)
#pragma unroll
    for (int r = 0; r < 4; ++r) { mrow[m2][r] = -1e30f; lrow[m2][r] = 0.f; }

  int nkt = 2 * qt + 2;
  for (int kt = 0; kt < nkt; ++kt) {
    int kb = kt * 64;
    // ---- stage K tile [64][128] via global_load_lds, source pre-swizzled ----
    const bf16_t* kg = qkv + (size_t)(b * 2048 + kb) * LD + 2048 + h * 128;
#pragma unroll
    for (int i = 0; i < 4; ++i) {
      int e = i * 256 + tid;
      int row = e >> 4, blk = e & 15;
      int src = (blk ^ (row & 7)) << 3;
      stage16(kg + (size_t)row * LD + src, Kt + e * 8);
    }
    // ---- stage V transposed: Vt[d][k], packed b32 writes, swizzled k-blocks ----
    const bf16_t* vg = qkv + (size_t)(b * 2048 + kb) * LD + 4096 + h * 128;
#pragma unroll
    for (int p = 0; p < 2; ++p) {
      int g = p * 256 + tid;
      int kv = (g >> 4) << 1;
      int d0 = (g & 15) << 3;
      us16x8 v0 = *(const us16x8*)(vg + (size_t)kv * LD + d0);
      us16x8 v1 = *(const us16x8*)(vg + (size_t)(kv + 1) * LD + d0);
      int k8 = kv >> 3, kr = kv & 7;
#pragma unroll
      for (int j = 0; j < 8; ++j) {
        int d = d0 + j;
        int swz = k8 ^ ((d ^ (d >> 3)) & 7);
        unsigned pack = (unsigned)v0[j] | ((unsigned)v1[j] << 16);
        *(unsigned*)(&Vt[d * 64 + swz * 8 + kr]) = pack;
      }
    }
    __syncthreads();

    if (kb < wq0 + 32) {  // wave-uniform: any unmasked element for this wave
      bool needMask = (kb + 63) > wq0;
      f32x4 s[2][4] = {};
#pragma unroll
      for (int kk = 0; kk < 4; ++kk) {
        bf16x8 kf[4];
        int blk = (kk * 4 + l4) ^ l7;
#pragma unroll
        for (int n = 0; n < 4; ++n)
          kf[n] = *(const bf16x8*)(Kt + (n * 16 + l15) * 128 + blk * 8);
#pragma unroll
        for (int m2 = 0; m2 < 2; ++m2)
#pragma unroll
          for (int n = 0; n < 4; ++n)
            s[m2][n] = MFMA16(qf[m2][kk], kf[n], s[m2][n]);
      }
      const float sc = 0.08838834764831845f;  // 1/sqrt(128)
      float scf[2][4];
#pragma unroll
      for (int m2 = 0; m2 < 2; ++m2) {
#pragma unroll
        for (int r = 0; r < 4; ++r) {
          int q = wq0 + m2 * 16 + (l4 << 2) + r;
#pragma unroll
          for (int n = 0; n < 4; ++n) {
            float v = s[m2][n][r] * sc;
            if (needMask && (kb + n * 16 + l15) > q) v = -1e30f;
            s[m2][n][r] = v;
          }
          float mx = fmaxf(fmaxf(s[m2][0][r], s[m2][1][r]), fmaxf(s[m2][2][r], s[m2][3][r]));
          mx = fmaxf(mx, __shfl_xor(mx, 1));
          mx = fmaxf(mx, __shfl_xor(mx, 2));
          mx = fmaxf(mx, __shfl_xor(mx, 4));
          mx = fmaxf(mx, __shfl_xor(mx, 8));
          float mn = fmaxf(mrow[m2][r], mx);
          float sf = __expf(mrow[m2][r] - mn);
          mrow[m2][r] = mn;
          scf[m2][r] = sf;
          float rs = 0.f;
#pragma unroll
          for (int n = 0; n < 4; ++n) {
            float pv = __expf(s[m2][n][r] - mn);
            s[m2][n][r] = pv;
            rs += pv;
          }
          rs += __shfl_xor(rs, 1);
          rs += __shfl_xor(rs, 2);
          rs += __shfl_xor(rs, 4);
          rs += __shfl_xor(rs, 8);
          lrow[m2][r] = lrow[m2][r] * sf + rs;
        }
      }
      // rescale accumulator
#pragma unroll
      for (int m2 = 0; m2 < 2; ++m2)
#pragma unroll
        for (int nd = 0; nd < 8; ++nd)
#pragma unroll
          for (int r = 0; r < 4; ++r)
            acc[m2][nd][r] *= scf[m2][r];
      // P (C-layout) -> LDS -> A-layout fragments
#pragma unroll
      for (int m2 = 0; m2 < 2; ++m2)
#pragma unroll
        for (int n = 0; n < 4; ++n)
#pragma unroll
          for (int r = 0; r < 4; ++r)
            Pl[w][(m2 * 16 + (l4 << 2) + r) * 72 + n * 16 + l15] = (bf16_t)s[m2][n][r];
      // PV
#pragma unroll
      for (int kk2 = 0; kk2 < 2; ++kk2) {
        bf16x8 pa0 = *(const bf16x8*)(&Pl[w][l15 * 72 + kk2 * 32 + l4 * 8]);
        bf16x8 pa1 = *(const bf16x8*)(&Pl[w][(16 + l15) * 72 + kk2 * 32 + l4 * 8]);
#pragma unroll
        for (int nd = 0; nd < 8; ++nd) {
          int d = nd * 16 + l15;
          int swz = (kk2 * 4 + l4) ^ ((d ^ (d >> 3)) & 7);
          bf16x8 bv = *(const bf16x8*)(&Vt[d * 64 + swz * 8]);
          acc[0][nd] = MFMA16(pa0, bv, acc[0][nd]);
          acc[1][nd] = MFMA16(pa1, bv, acc[1][nd]);
        }
      }
    }
    __syncthreads();
  }

  // epilogue: O /= l, write bf16
#pragma unroll
  for (int m2 = 0; m2 < 2; ++m2)
#pragma unroll
    for (int r = 0; r < 4; ++r) {
      float inv = 1.0f / lrow[m2][r];
      size_t rowoff = (size_t)(b * 2048 + wq0 + m2 * 16 + (l4 << 2) + r) * 2048 + h * 128;
#pragma unroll
      for (int nd = 0; nd < 8; ++nd)
        att[rowoff + nd * 16 + l15] = (bf16_t)(acc[m2][nd][r] * inv);
    }
}

// ---------------- launch ----------------
extern "C" void kernel_launch(void* const* d_in, const int* in_sizes, int n_in,
                              void* d_out, int out_size, void* d_ws, size_t ws_size,
                              hipStream_t stream) {
  (void)in_sizes; (void)n_in; (void)out_size; (void)ws_size;
  const float* x = (const float*)d_in[0];
  const float* w_attn = (const float*)d_in[1];
  const float* b_attn = (const float*)d_in[2];
  const float* w_proj = (const float*)d_in[3];
  const float* b_proj = (const float*)d_in[4];
  float* out = (float*)d_out;

  char* ws = (char*)d_ws;
  // workspace layout (bytes):
  //  xb   @ 0         : 4096*2048*2  = 16,777,216   (reused as att after GEMM1)
  //  wab  @ 16777216  : 6144*2048*2  = 25,165,824
  //  wpb  @ 41943040  : 2048*2048*2  =  8,388,608
  //  qkv  @ 50331648  : 4096*6144*2  = 50,331,648
  //  total = 100,663,296 (96 MiB)
  bf16_t* xb  = (bf16_t*)(ws);
  bf16_t* wab = (bf16_t*)(ws + 16777216);
  bf16_t* wpb = (bf16_t*)(ws + 41943040);
  bf16_t* qkv = (bf16_t*)(ws + 50331648);
  bf16_t* att = xb;  // xb dead after GEMM1

  cvt_f32_to_bf16<<<4096, 256, 0, stream>>>(x, xb, 1048576);       // 8,388,608 elems
  cvt_f32_to_bf16<<<6144, 256, 0, stream>>>(w_attn, wab, 1572864); // 12,582,912
  cvt_f32_to_bf16<<<2048, 256, 0, stream>>>(w_proj, wpb, 524288);  // 4,194,304

  // qkv = x @ w_attn^T + b_attn  -> bf16 [4096, 6144]
  gemm_nt<1><<<32 * 48, 256, 0, stream>>>(xb, wab, b_attn, qkv, 4096, 6144, 2048);

  // causal flash attention -> att bf16 [4096, 2048]
  attn_fwd<<<512, 256, 0, stream>>>(qkv, att);

  // out = att @ w_proj^T + b_proj -> f32 [4096, 2048]
  gemm_nt<0><<<32 * 16, 256, 0, stream>>>(att, wpb, b_proj, out, 4096, 2048, 2048);
}

// Round 2
// 286.976 us; speedup vs baseline: 1.6036x; 1.6036x over previous
//
#include <hip/hip_runtime.h>
#include <stdint.h>

typedef __bf16 bf16_t;
typedef __bf16 bf16x8 __attribute__((ext_vector_type(8)));
typedef float f32x4 __attribute__((ext_vector_type(4)));
typedef unsigned short us16x8 __attribute__((ext_vector_type(8)));

#define MFMA16(a, b, c) __builtin_amdgcn_mfma_f32_16x16x32_bf16(a, b, c, 0, 0, 0)

__device__ __forceinline__ void stage16(const bf16_t* g, bf16_t* l) {
#if __has_builtin(__builtin_amdgcn_global_load_lds)
  __builtin_amdgcn_global_load_lds((__attribute__((address_space(1))) void*)g,
                                   (__attribute__((address_space(3))) void*)l, 16, 0, 0);
#else
  *(bf16x8*)l = *(const bf16x8*)g;
#endif
}

// ---------------- f32 -> bf16 conversion ----------------
__global__ __launch_bounds__(256) void cvt_f32_to_bf16(const float* __restrict__ in,
                                                       bf16_t* __restrict__ out, int n8) {
  int i = blockIdx.x * 256 + threadIdx.x;
  if (i >= n8) return;
  const f32x4* p = (const f32x4*)(in + (size_t)i * 8);
  f32x4 a = p[0], b = p[1];
  bf16x8 o;
  o[0] = (bf16_t)a[0]; o[1] = (bf16_t)a[1]; o[2] = (bf16_t)a[2]; o[3] = (bf16_t)a[3];
  o[4] = (bf16_t)b[0]; o[5] = (bf16_t)b[1]; o[6] = (bf16_t)b[2]; o[7] = (bf16_t)b[3];
  *(bf16x8*)(out + (size_t)i * 8) = o;
}

// ---------------- NT GEMM: C[M,N] = A[M,K] * B[N,K]^T + bias ----------------
// 128x128 tile, BK=64, 4 waves (2x2), each wave 64x64 (4x4 16x16 frags).
template <int OUT_BF16>
__global__ __launch_bounds__(256) void gemm_nt(const bf16_t* __restrict__ A,
                                               const bf16_t* __restrict__ B,
                                               const float* __restrict__ bias,
                                               void* __restrict__ Cout,
                                               int M, int N, int K) {
  __shared__ bf16_t As[128 * 64];
  __shared__ bf16_t Bs[128 * 64];
  int tid = threadIdx.x;
  int l = tid & 63, w = tid >> 6;
  int wr = w >> 1, wc = w & 1;
  int nbn = N >> 7;
  int bm = blockIdx.x / nbn, bn = blockIdx.x % nbn;
  int l15 = l & 15, l4 = l >> 4, l7 = l & 7;

  f32x4 acc[4][4] = {};

  for (int ks = 0; ks < K; ks += 64) {
#pragma unroll
    for (int i = 0; i < 4; ++i) {
      int e = i * 256 + tid;
      int row = e >> 3, blk = e & 7;
      int col = ks + ((blk ^ (row & 7)) << 3);
      stage16(A + (size_t)(bm * 128 + row) * K + col, As + e * 8);
      stage16(B + (size_t)(bn * 128 + row) * K + col, Bs + e * 8);
    }
    __syncthreads();
#pragma unroll
    for (int kk = 0; kk < 2; ++kk) {
      bf16x8 af[4], bfr[4];
      int blk = (kk * 4 + l4) ^ l7;
#pragma unroll
      for (int m = 0; m < 4; ++m) {
        af[m] = *(const bf16x8*)(As + (wr * 64 + m * 16 + l15) * 64 + blk * 8);
        bfr[m] = *(const bf16x8*)(Bs + (wc * 64 + m * 16 + l15) * 64 + blk * 8);
      }
#pragma unroll
      for (int m = 0; m < 4; ++m)
#pragma unroll
        for (int n = 0; n < 4; ++n)
          acc[m][n] = MFMA16(af[m], bfr[n], acc[m][n]);
    }
    __syncthreads();
  }

  int rbase = bm * 128 + wr * 64 + (l4 << 2);
  int cbase = bn * 128 + wc * 64 + l15;
#pragma unroll
  for (int n = 0; n < 4; ++n) {
    float bv = bias[cbase + n * 16];
#pragma unroll
    for (int m = 0; m < 4; ++m)
#pragma unroll
      for (int r = 0; r < 4; ++r) {
        float v = acc[m][n][r] + bv;
        size_t off = (size_t)(rbase + m * 16 + r) * N + (cbase + n * 16);
        if (OUT_BF16) ((bf16_t*)Cout)[off] = (bf16_t)v;
        else ((float*)Cout)[off] = v;
      }
  }
}

// ---------------- causal flash attention ----------------
// qkv: [4096, 6144] bf16 (q at col h*128, k at 2048+h*128, v at 4096+h*128)
// att: [4096, 2048] bf16.
// Block = (pair i, b, h): processes q-tile i then q-tile 31-i (QBLK=64 each,
// 4 waves x 16 q-rows) -> uniform 33 K-tile steps per block (zero tail).
// bid = pair*32 + bh so bid%8 = bh%8: same-(b,h) blocks land on one XCD ->
// that XCD's L2 (4MB) holds its 4 heads' K/V (4x1MB) across re-reads.
__global__ __launch_bounds__(256, 2) void attn_fwd(const bf16_t* __restrict__ qkv,
                                                   bf16_t* __restrict__ att) {
  __shared__ bf16_t Kt[64 * 128];    // [krow][d], 16B-block-swizzled rows
  __shared__ bf16_t Vt[128 * 64];    // transposed [d][k], swizzled k-blocks
  __shared__ bf16_t Pw[4][16 * 64];  // per-wave P, swizzled (row&7 XOR on col-block)

  int bid = blockIdx.x;
  int pair = bid >> 5, bh = bid & 31;
  int h = bh & 15, b = bh >> 4;
  int tid = threadIdx.x;
  int l = tid & 63, w = tid >> 6;
  int l15 = l & 15, l4 = l >> 4, l7 = l & 7;
  const size_t LD = 6144;
  const bf16_t* base = qkv + (size_t)b * 2048 * LD;

#pragma unroll 1
  for (int phase = 0; phase < 2; ++phase) {
    int qt = phase ? 31 - pair : pair;
    int q0 = qt << 6;
    int wq0 = q0 + w * 16;

    // Q fragments in registers (A-operand layout, 16 rows/wave)
    bf16x8 qf[4];
#pragma unroll
    for (int kk = 0; kk < 4; ++kk)
      qf[kk] = *(const bf16x8*)(base + (size_t)(wq0 + l15) * LD + h * 128 + kk * 32 + l4 * 8);

    f32x4 acc[8] = {};
    float mrow[4], lrow[4];
#pragma unroll
    for (int r = 0; r < 4; ++r) { mrow[r] = -1e30f; lrow[r] = 0.f; }

    int nkt = qt + 1;
    for (int kt = 0; kt < nkt; ++kt) {
      int kb = kt << 6;
      // ---- V loads issued FIRST (latency hides under K-issue + pack) ----
      const bf16_t* vg = base + (size_t)kb * LD + 4096 + h * 128;
      us16x8 va[2], vb[2];
#pragma unroll
      for (int p = 0; p < 2; ++p) {
        int g = p * 256 + tid;
        int kv = (g >> 4) << 1;
        int d0 = (g & 15) << 3;
        va[p] = *(const us16x8*)(vg + (size_t)kv * LD + d0);
        vb[p] = *(const us16x8*)(vg + (size_t)(kv + 1) * LD + d0);
      }
      // ---- K tile [64][128] via global_load_lds, source pre-swizzled ----
      const bf16_t* kg = base + (size_t)kb * LD + 2048 + h * 128;
#pragma unroll
      for (int i = 0; i < 4; ++i) {
        int e = i * 256 + tid;
        int row = e >> 4, blk = e & 15;
        int src = (blk ^ (row & 7)) << 3;
        stage16(kg + (size_t)row * LD + src, Kt + e * 8);
      }
      // ---- V transpose writes (packed b32, swizzled) ----
#pragma unroll
      for (int p = 0; p < 2; ++p) {
        int g = p * 256 + tid;
        int kv = (g >> 4) << 1;
        int d0 = (g & 15) << 3;
        int k8 = kv >> 3, kr = kv & 7;
#pragma unroll
        for (int j = 0; j < 8; ++j) {
          int d = d0 + j;
          int swz = k8 ^ ((d ^ (d >> 3)) & 7);
          unsigned pack = (unsigned)va[p][j] | ((unsigned)vb[p][j] << 16);
          *(unsigned*)(&Vt[d * 64 + swz * 8 + kr]) = pack;
        }
      }
      __syncthreads();

      // ---- QK^T ----
      f32x4 s[4] = {};
      __builtin_amdgcn_s_setprio(1);
#pragma unroll
      for (int kk = 0; kk < 4; ++kk) {
        int blk = (kk * 4 + l4) ^ l7;
#pragma unroll
        for (int n = 0; n < 4; ++n) {
          bf16x8 kf = *(const bf16x8*)(Kt + (n * 16 + l15) * 128 + blk * 8);
          s[n] = MFMA16(qf[kk], kf, s[n]);
        }
      }
      __builtin_amdgcn_s_setprio(0);

      // ---- online softmax (rows = l4*4+r, 16 lanes per row) ----
      const float sc = 0.08838834764831845f;  // 1/sqrt(128)
      bool needMask = (kb + 63) > wq0;
      float scf[4];
#pragma unroll
      for (int r = 0; r < 4; ++r) {
        int q = wq0 + (l4 << 2) + r;
#pragma unroll
        for (int n = 0; n < 4; ++n) {
          float v = s[n][r] * sc;
          if (needMask && (kb + n * 16 + l15) > q) v = -1e30f;
          s[n][r] = v;
        }
        float mx = fmaxf(fmaxf(s[0][r], s[1][r]), fmaxf(s[2][r], s[3][r]));
        mx = fmaxf(mx, __shfl_xor(mx, 1));
        mx = fmaxf(mx, __shfl_xor(mx, 2));
        mx = fmaxf(mx, __shfl_xor(mx, 4));
        mx = fmaxf(mx, __shfl_xor(mx, 8));
        float mn = fmaxf(mrow[r], mx);
        float sf = __expf(mrow[r] - mn);
        mrow[r] = mn;
        scf[r] = sf;
        float rs = 0.f;
#pragma unroll
        for (int n = 0; n < 4; ++n) {
          float pv = __expf(s[n][r] - mn);
          s[n][r] = pv;
          rs += pv;
        }
        rs += __shfl_xor(rs, 1);
        rs += __shfl_xor(rs, 2);
        rs += __shfl_xor(rs, 4);
        rs += __shfl_xor(rs, 8);
        lrow[r] = lrow[r] * sf + rs;
      }
      // rescale accumulator
#pragma unroll
      for (int nd = 0; nd < 8; ++nd)
#pragma unroll
        for (int r = 0; r < 4; ++r)
          acc[nd][r] *= scf[r];
      // ---- P (C-layout) -> per-wave LDS, swizzled [16][64] ----
#pragma unroll
      for (int n = 0; n < 4; ++n) {
        int cb8 = n * 2 + (l15 >> 3);
#pragma unroll
        for (int r = 0; r < 4; ++r) {
          int row = (l4 << 2) + r;
          Pw[w][row * 64 + ((cb8 ^ (row & 7)) << 3) + l7] = (bf16_t)s[n][r];
        }
      }
      // ---- PV ----
      __builtin_amdgcn_s_setprio(1);
#pragma unroll
      for (int kk2 = 0; kk2 < 2; ++kk2) {
        bf16x8 pa = *(const bf16x8*)(&Pw[w][l15 * 64 + (((kk2 * 4 + l4) ^ l7) << 3)]);
#pragma unroll
        for (int nd = 0; nd < 8; ++nd) {
          int d = nd * 16 + l15;
          int swz = (kk2 * 4 + l4) ^ ((d ^ (d >> 3)) & 7);
          bf16x8 bv = *(const bf16x8*)(&Vt[d * 64 + swz * 8]);
          acc[nd] = MFMA16(pa, bv, acc[nd]);
        }
      }
      __builtin_amdgcn_s_setprio(0);
      __syncthreads();
    }

    // ---- epilogue: O /= l, write bf16 ----
#pragma unroll
    for (int r = 0; r < 4; ++r) {
      float inv = 1.0f / lrow[r];
      size_t ro = (size_t)(b * 2048 + wq0 + (l4 << 2) + r) * 2048 + h * 128;
#pragma unroll
      for (int nd = 0; nd < 8; ++nd)
        att[ro + nd * 16 + l15] = (bf16_t)(acc[nd][r] * inv);
    }
  }
}

// ---------------- launch ----------------
extern "C" void kernel_launch(void* const* d_in, const int* in_sizes, int n_in,
                              void* d_out, int out_size, void* d_ws, size_t ws_size,
                              hipStream_t stream) {
  (void)in_sizes; (void)n_in; (void)out_size; (void)ws_size;
  const float* x = (const float*)d_in[0];
  const float* w_attn = (const float*)d_in[1];
  const float* b_attn = (const float*)d_in[2];
  const float* w_proj = (const float*)d_in[3];
  const float* b_proj = (const float*)d_in[4];
  float* out = (float*)d_out;

  char* ws = (char*)d_ws;
  // workspace layout (bytes):
  //  xb   @ 0         : 4096*2048*2  = 16,777,216   (reused as att after GEMM1)
  //  wab  @ 16777216  : 6144*2048*2  = 25,165,824
  //  wpb  @ 41943040  : 2048*2048*2  =  8,388,608
  //  qkv  @ 50331648  : 4096*6144*2  = 50,331,648
  bf16_t* xb  = (bf16_t*)(ws);
  bf16_t* wab = (bf16_t*)(ws + 16777216);
  bf16_t* wpb = (bf16_t*)(ws + 41943040);
  bf16_t* qkv = (bf16_t*)(ws + 50331648);
  bf16_t* att = xb;  // xb dead after GEMM1

  cvt_f32_to_bf16<<<4096, 256, 0, stream>>>(x, xb, 1048576);
  cvt_f32_to_bf16<<<6144, 256, 0, stream>>>(w_attn, wab, 1572864);
  cvt_f32_to_bf16<<<2048, 256, 0, stream>>>(w_proj, wpb, 524288);

  // qkv = x @ w_attn^T + b_attn  -> bf16 [4096, 6144]
  gemm_nt<1><<<32 * 48, 256, 0, stream>>>(xb, wab, b_attn, qkv, 4096, 6144, 2048);

  // causal flash attention -> att bf16 [4096, 2048]
  attn_fwd<<<512, 256, 0, stream>>>(qkv, att);

  // out = att @ w_proj^T + b_proj -> f32 [4096, 2048]
  gemm_nt<0><<<32 * 16, 256, 0, stream>>>(att, wpb, b_proj, out, 4096, 2048, 2048);
}